// Round 14
// baseline (42.600 us; speedup 1.0000x reference)
//
#include <hip/hip_runtime.h>
#include <hip/hip_bf16.h>

#define B_ 8
#define T_ 2048
#define V_ 256
#define D_ 512
#define LEFT_ 16

typedef float f32x4 __attribute__((ext_vector_type(4)));
typedef short bf16x8 __attribute__((ext_vector_type(8)));
typedef unsigned long long u64;
union FragU { unsigned u[4]; u64 ull[2]; bf16x8 v; uint4 q4; };

__device__ __forceinline__ unsigned pack_bf2(float a, float b) {
    __hip_bfloat162 h = __float22bfloat162_rn(make_float2(a, b));
    union { __hip_bfloat162 h; unsigned u; } c; c.h = h; return c.u;
}

// ---- prep: pack M and C into MFMA-B/A fragment tables (bf16) in workspace ----
// Mf granule i = (ks*4+q)*256 + v : elems e = M[v][ks*32 + 4q + (e&3) + 16*(e>>2)]
// Cf granule i = (vs*4+q)*512 + d : elems e = C[vs*32 + 4q + (e&3) + 16*(e>>2)][d]
__global__ __launch_bounds__(256)
void prep_kernel(const float* __restrict__ M, const float* __restrict__ C,
                 uint4* __restrict__ Mf, uint4* __restrict__ Cf) {
    const int i = blockIdx.x * 256 + threadIdx.x;    // 0..16383
    {
        const int ks = i >> 10, q = (i >> 8) & 3, v = i & 255;
        const int k0 = ks * 32 + 4 * q;
        const float4 a = *(const float4*)&M[v * D_ + k0];
        const float4 b = *(const float4*)&M[v * D_ + k0 + 16];
        Mf[i] = make_uint4(pack_bf2(a.x, a.y), pack_bf2(a.z, a.w),
                           pack_bf2(b.x, b.y), pack_bf2(b.z, b.w));
    }
    {
        const int vs = i >> 11, q = (i >> 9) & 3, d = i & 511;
        const int v0 = vs * 32 + 4 * q;
        float c[8];
        #pragma unroll
        for (int e = 0; e < 4; ++e) c[e]     = C[(size_t)(v0 + e) * D_ + d];
        #pragma unroll
        for (int e = 0; e < 4; ++e) c[4 + e] = C[(size_t)(v0 + 16 + e) * D_ + d];
        Cf[i] = make_uint4(pack_bf2(c[0], c[1]), pack_bf2(c[2], c[3]),
                           pack_bf2(c[4], c[5]), pack_bf2(c[6], c[7]));
    }
}

// ---- main: block = 32 tokens, 512 threads (8 waves), 2 blocks/CU, grid 512 ----
// LDS: [0,32768) E bf16 [32][512] XOR-swizzled (R11 pattern), aliased by S f32 [32][256]
//      [32768,65536) P f32 [32][256], 16B-granule XOR-swizzled by (t&7)
__global__ __launch_bounds__(512)
void attn_cell_kernel(const int* __restrict__ symbols,
                      const float* __restrict__ encodings,
                      const uint4* __restrict__ Mf,
                      const uint4* __restrict__ Cf,
                      float* __restrict__ out,      // (B,T,1024)
                      float* __restrict__ p_out) {  // (B,T,16)
    __shared__ __align__(16) char smem[65536];
    u64*   e8 = (u64*)smem;
    float* S  = (float*)smem;
    float* P  = (float*)(smem + 32768);

    const int tid  = threadIdx.x;
    const int lane = tid & 63;
    const int w    = tid >> 6;      // 0..7
    const int q    = lane >> 4;     // 0..3
    const int lv   = lane & 15;

    const int blk = blockIdx.x;
    const int b   = blk >> 6;                 // 64 blocks per batch row
    const int t0  = (blk & 63) * 32;
    const size_t rowbase = (size_t)b * T_ + t0;

    // ---- stage E (bf16, XOR-swz) + exact f32 passthrough + zero P ----
    #pragma unroll
    for (int iter = 0; iter < 4; ++iter) {
        const int idx  = iter * 512 + tid;
        const int trow = idx >> 6;            // 0..31
        const int g    = idx & 63;            // 16B granule
        const float* src = encodings + (rowbase + trow) * D_ + g * 8;
        const float4 v0 = ((const float4*)src)[0];
        const float4 v1 = ((const float4*)src)[1];
        float* dst = out + (rowbase + trow) * 1024 + D_ + g * 8;
        ((float4*)dst)[0] = v0;
        ((float4*)dst)[1] = v1;
        const u64 lo = (u64)pack_bf2(v0.x, v0.y) | ((u64)pack_bf2(v0.z, v0.w) << 32);
        const u64 hi = (u64)pack_bf2(v1.x, v1.y) | ((u64)pack_bf2(v1.z, v1.w) << 32);
        const int c = trow & 7;
        e8[trow * 128 + ((2 * g)     ^ c)] = lo;
        e8[trow * 128 + ((2 * g + 1) ^ c)] = hi;
        ((uint4*)P)[iter * 512 + tid] = make_uint4(0u, 0u, 0u, 0u);
    }
    __syncthreads();

    // ---- GEMM1: S[32 t][256 v] = E · M^T; wave w owns v-tiles {2w, 2w+1} ----
    f32x4 accS[2][2] = {};                    // [vtile][ttile]
    {
        const int c = lv & 7;                 // row&7 for both t-tiles (16 ≡ 0 mod 8)
        #pragma unroll
        for (int ks = 0; ks < 16; ++ks) {
            const int gb = ks * 8 + q;
            FragU a0, a1;
            a0.ull[0] = e8[lv * 128        + ((gb)     ^ c)];
            a0.ull[1] = e8[lv * 128        + ((gb + 4) ^ c)];
            a1.ull[0] = e8[(16 + lv) * 128 + ((gb)     ^ c)];
            a1.ull[1] = e8[(16 + lv) * 128 + ((gb + 4) ^ c)];
            FragU b0, b1;
            b0.q4 = Mf[(ks * 4 + q) * 256 + (2 * w)     * 16 + lv];
            b1.q4 = Mf[(ks * 4 + q) * 256 + (2 * w + 1) * 16 + lv];
            accS[0][0] = __builtin_amdgcn_mfma_f32_16x16x32_bf16(a0.v, b0.v, accS[0][0], 0, 0, 0);
            accS[0][1] = __builtin_amdgcn_mfma_f32_16x16x32_bf16(a1.v, b0.v, accS[0][1], 0, 0, 0);
            accS[1][0] = __builtin_amdgcn_mfma_f32_16x16x32_bf16(a0.v, b1.v, accS[1][0], 0, 0, 0);
            accS[1][1] = __builtin_amdgcn_mfma_f32_16x16x32_bf16(a1.v, b1.v, accS[1][1], 0, 0, 0);
        }
    }
    __syncthreads();   // all E reads done before S overwrites the same LDS

    // D map (verified R10-12): col = lv (v-low), row = 4q+r (t-low)
    #pragma unroll
    for (int vti = 0; vti < 2; ++vti)
        #pragma unroll
        for (int tti = 0; tti < 2; ++tti)
            #pragma unroll
            for (int r = 0; r < 4; ++r)
                S[(tti * 16 + 4 * q + r) * 256 + (2 * w + vti) * 16 + lv] = accS[vti][tti][r];
    __syncthreads();

    // ---- band gather + softmax + P scatter: thread = (token tt, slot j) ----
    {
        const int tt = tid >> 4;              // 0..31
        const int j  = tid & 15;              // == lane&15
        int pos = t0 + tt - (LEFT_ - 1) + j;
        pos = max(pos, 0);
        const int sym = symbols[b * T_ + pos];
        const float s = S[tt * 256 + sym];
        float mx = s;
        mx = fmaxf(mx, __shfl_xor(mx, 1));
        mx = fmaxf(mx, __shfl_xor(mx, 2));
        mx = fmaxf(mx, __shfl_xor(mx, 4));
        mx = fmaxf(mx, __shfl_xor(mx, 8));
        const float ex = __expf(s - mx);
        float sum = ex;
        sum += __shfl_xor(sum, 1);
        sum += __shfl_xor(sum, 2);
        sum += __shfl_xor(sum, 4);
        sum += __shfl_xor(sum, 8);
        const float p = ex / sum;
        p_out[(rowbase + tt) * 16 + j] = p;
        // swizzled scatter; atomicAdd handles duplicate symbols in the window
        atomicAdd(&P[tt * 256 + (((sym >> 2) ^ (tt & 7)) << 2) + (sym & 3)], p);
    }
    __syncthreads();

    // ---- GEMM2: O^T[d][t] = C^T · P^T; wave w owns d-tiles w*4..w*4+3 ----
    f32x4 accO[4][2] = {};                    // [m][ttile]
    #pragma unroll
    for (int vs = 0; vs < 8; ++vs) {
        FragU bp[2];
        #pragma unroll
        for (int tti = 0; tti < 2; ++tti) {
            const int t  = tti * 16 + lv;
            const int ct = lv & 7;
            const int g0 = vs * 8 + q;
            const f32x4 pa = *(const f32x4*)&P[t * 256 + ((g0       ^ ct) << 2)];
            const f32x4 pb = *(const f32x4*)&P[t * 256 + (((g0 + 4) ^ ct) << 2)];
            bp[tti].u[0] = pack_bf2(pa[0], pa[1]); bp[tti].u[1] = pack_bf2(pa[2], pa[3]);
            bp[tti].u[2] = pack_bf2(pb[0], pb[1]); bp[tti].u[3] = pack_bf2(pb[2], pb[3]);
        }
        #pragma unroll
        for (int m = 0; m < 4; ++m) {
            FragU ac;
            ac.q4 = Cf[(vs * 4 + q) * 512 + (w * 4 + m) * 16 + lv];
            #pragma unroll
            for (int tti = 0; tti < 2; ++tti)
                accO[m][tti] = __builtin_amdgcn_mfma_f32_16x16x32_bf16(ac.v, bp[tti].v, accO[m][tti], 0, 0, 0);
        }
    }
    // D map: col = lv = t-low, row = 4q+r = d-low -> float4 store over r
    #pragma unroll
    for (int m = 0; m < 4; ++m)
        #pragma unroll
        for (int tti = 0; tti < 2; ++tti) {
            float* ob = out + (rowbase + tti * 16 + lv) * 1024 + (w * 4 + m) * 16 + 4 * q;
            *(float4*)ob = make_float4(accO[m][tti][0], accO[m][tti][1],
                                       accO[m][tti][2], accO[m][tti][3]);
        }
}

extern "C" void kernel_launch(void* const* d_in, const int* in_sizes, int n_in,
                              void* d_out, int out_size, void* d_ws, size_t ws_size,
                              hipStream_t stream) {
    const int*   symbols   = (const int*)d_in[0];
    const float* encodings = (const float*)d_in[1];
    const float* M         = (const float*)d_in[2];
    const float* C         = (const float*)d_in[3];
    float* out   = (float*)d_out;
    float* p_out = out + (size_t)B_ * T_ * 1024;   // concat order: output, then p

    uint4* Mf = (uint4*)d_ws;                        // 256 KB
    uint4* Cf = (uint4*)((char*)d_ws + 262144);      // 256 KB

    prep_kernel<<<64, 256, 0, stream>>>(M, C, Mf, Cf);
    attn_cell_kernel<<<512, 512, 0, stream>>>(symbols, encodings, Mf, Cf, out, p_out);
}

// Round 15
// 32.741 us; speedup vs baseline: 1.3011x; 1.3011x over previous
//
#include <hip/hip_runtime.h>
#include <hip/hip_bf16.h>

#define B_ 8
#define T_ 2048
#define V_ 256
#define D_ 512
#define LEFT_ 16

typedef float f32x4 __attribute__((ext_vector_type(4)));
typedef short bf16x8 __attribute__((ext_vector_type(8)));
typedef unsigned long long u64;
union FragU { unsigned u[4]; u64 ull[2]; bf16x8 v; };

__device__ __forceinline__ unsigned pack_bf2(float a, float b) {
    __hip_bfloat162 h = __float22bfloat162_rn(make_float2(a, b));
    union { __hip_bfloat162 h; unsigned u; } c; c.h = h; return c.u;
}

// Block = 16 tokens, 8 waves, ONE barrier, NO operand staging in LDS.
// Pre-barrier: enc load (fused f32 passthrough) -> B-frags; C fragments
//   prefetched straight from L2 into packed bf16 regs (independent of softmax);
//   phase A S_ext partials via MFMA with M read directly from L2; partials -> sp.
// Post-barrier: reduce 8 slices, masked band softmax, in-lane p handoff
//   (R10/R11/R12-verified), phase B MFMA from prefetched regs, stores.
// LDS = 18432 B only -> 4 blocks/CU (thread-capped), whole grid resident.
__global__ __launch_bounds__(512)
void attn_cell_kernel(const int* __restrict__ symbols,
                      const float* __restrict__ encodings,
                      const float* __restrict__ M,
                      const float* __restrict__ C,
                      float* __restrict__ out,      // (B,T,1024)
                      float* __restrict__ p_out) {  // (B,T,16)
    __shared__ __align__(16) float sp[8 * 16 * 36];            // 18432 B

    const int tid  = threadIdx.x;
    const int lane = tid & 63;
    const int w    = tid >> 6;      // 0..7
    const int q    = lane >> 4;     // 0..3
    const int t    = lane & 15;

    const int blk = blockIdx.x;
    const int b   = blk >> 7;
    const int t0  = (blk & 127) * 16;
    const int* symrow = symbols + b * T_;
    const size_t rowbase = (size_t)b * T_ + t0;

    // phase-A symbols: rows j = t and t+16
    int sa[2];
    #pragma unroll
    for (int g = 0; g < 2; ++g) {
        int pos = t0 + t + 16 * g - (LEFT_ - 1);
        pos = max(pos, 0); pos = min(pos, T_ - 1);
        sa[g] = symrow[pos];
    }
    // phase-B symbols: k-elems j(e) = 4q + (e&3) + 16*(e>>2)  (R10-verified map)
    int sb[8];
    #pragma unroll
    for (int e = 0; e < 8; ++e) {
        const int j = 4 * q + (e & 3) + 16 * (e >> 2);
        int pos = t0 + j - (LEFT_ - 1);
        pos = max(pos, 0); pos = min(pos, T_ - 1);
        sb[e] = symrow[pos];
    }

    // ---- enc load, fused exact-f32 passthrough, pack B-fragments ----
    FragU bf[2];
    {
        const float* ebase = encodings + (rowbase + t) * D_;
        float* obase = out + (rowbase + t) * 1024 + D_;
        #pragma unroll
        for (int kc = 0; kc < 2; ++kc) {
            const int d0 = 64 * w + 32 * kc + 4 * q;
            const float4 e0 = *(const float4*)(ebase + d0);
            const float4 e1 = *(const float4*)(ebase + d0 + 16);
            *(float4*)(obase + d0)      = e0;
            *(float4*)(obase + d0 + 16) = e1;
            bf[kc].u[0] = pack_bf2(e0.x, e0.y); bf[kc].u[1] = pack_bf2(e0.z, e0.w);
            bf[kc].u[2] = pack_bf2(e1.x, e1.y); bf[kc].u[3] = pack_bf2(e1.z, e1.w);
        }
    }

    // ---- prefetch phase-B C fragments from L2 into packed bf16 regs ----
    FragU afc[4];
    #pragma unroll
    for (int m = 0; m < 4; ++m) {
        const int dA = (w * 4 + m) * 16 + t;
        float c[8];
        #pragma unroll
        for (int e = 0; e < 8; ++e)
            c[e] = C[(size_t)sb[e] * D_ + dA];
        afc[m].u[0] = pack_bf2(c[0], c[1]); afc[m].u[1] = pack_bf2(c[2], c[3]);
        afc[m].u[2] = pack_bf2(c[4], c[5]); afc[m].u[3] = pack_bf2(c[6], c[7]);
    }

    // ---- phase A: MFMA partials, M fragments straight from L2 (R10-verified) ----
    f32x4 acc0 = {0.f, 0.f, 0.f, 0.f}, acc1 = {0.f, 0.f, 0.f, 0.f};
    #pragma unroll
    for (int kc = 0; kc < 2; ++kc) {
        const int k0 = 64 * w + 32 * kc + 4 * q;
        {
            const float* ma = M + (size_t)sa[0] * D_ + k0;
            const float4 x0 = *(const float4*)ma;
            const float4 x1 = *(const float4*)(ma + 16);
            FragU af;
            af.u[0] = pack_bf2(x0.x, x0.y); af.u[1] = pack_bf2(x0.z, x0.w);
            af.u[2] = pack_bf2(x1.x, x1.y); af.u[3] = pack_bf2(x1.z, x1.w);
            acc0 = __builtin_amdgcn_mfma_f32_16x16x32_bf16(af.v, bf[kc].v, acc0, 0, 0, 0);
        }
        {
            const float* ma = M + (size_t)sa[1] * D_ + k0;
            const float4 x0 = *(const float4*)ma;
            const float4 x1 = *(const float4*)(ma + 16);
            FragU af;
            af.u[0] = pack_bf2(x0.x, x0.y); af.u[1] = pack_bf2(x0.z, x0.w);
            af.u[2] = pack_bf2(x1.x, x1.y); af.u[3] = pack_bf2(x1.z, x1.w);
            acc1 = __builtin_amdgcn_mfma_f32_16x16x32_bf16(af.v, bf[kc].v, acc1, 0, 0, 0);
        }
    }
    *(f32x4*)&sp[(w * 16 + t) * 36 + 4 * q]      = acc0;  // j = 4q+r
    *(f32x4*)&sp[(w * 16 + t) * 36 + 16 + 4 * q] = acc1;  // j = 16+4q+r

    __syncthreads();   // the only barrier

    // ---- reduce 8 slices; masked softmax; in-lane p handoff (verified) ----
    FragU pf;
    {
        f32x4 s0 = *(const f32x4*)&sp[t * 36 + 4 * q];
        f32x4 s1 = *(const f32x4*)&sp[t * 36 + 16 + 4 * q];
        #pragma unroll
        for (int w2 = 1; w2 < 8; ++w2) {
            s0 += *(const f32x4*)&sp[(w2 * 16 + t) * 36 + 4 * q];
            s1 += *(const f32x4*)&sp[(w2 * 16 + t) * 36 + 16 + 4 * q];
        }
        float mx = -3.0e38f;
        #pragma unroll
        for (int r = 0; r < 4; ++r) {
            if ((unsigned)(4 * q + r - t) < 16u)      mx = fmaxf(mx, s0[r]);
            if ((unsigned)(4 * q + r + 16 - t) < 16u) mx = fmaxf(mx, s1[r]);
        }
        mx = fmaxf(mx, __shfl_xor(mx, 16));
        mx = fmaxf(mx, __shfl_xor(mx, 32));
        float p0[4], p1[4];
        float sum = 0.f;
        #pragma unroll
        for (int r = 0; r < 4; ++r) {
            const bool m0 = (unsigned)(4 * q + r - t) < 16u;
            const bool m1 = (unsigned)(4 * q + r + 16 - t) < 16u;
            p0[r] = m0 ? __expf(s0[r] - mx) : 0.f;
            p1[r] = m1 ? __expf(s1[r] - mx) : 0.f;
            sum += p0[r] + p1[r];
        }
        sum += __shfl_xor(sum, 16);
        sum += __shfl_xor(sum, 32);
        const float inv = 1.f / sum;
        #pragma unroll
        for (int r = 0; r < 4; ++r) { p0[r] *= inv; p1[r] *= inv; }

        if (w == 0) {
            #pragma unroll
            for (int r = 0; r < 4; ++r) {
                const int j0 = 4 * q + r;
                if ((unsigned)(j0 - t) < 16u)
                    p_out[(rowbase + t) * 16 + (j0 - t)] = p0[r];
                else
                    p_out[(rowbase + t) * 16 + (j0 + 16 - t)] = p1[r];
            }
        }
        pf.u[0] = pack_bf2(p0[0], p0[1]); pf.u[1] = pack_bf2(p0[2], p0[3]);
        pf.u[2] = pack_bf2(p1[0], p1[1]); pf.u[3] = pack_bf2(p1[2], p1[3]);
    }

    // ---- phase B: MFMA from prefetched C fragments (no LDS) ----
    #pragma unroll
    for (int m = 0; m < 4; ++m) {
        f32x4 o = {0.f, 0.f, 0.f, 0.f};
        o = __builtin_amdgcn_mfma_f32_16x16x32_bf16(afc[m].v, pf.v, o, 0, 0, 0);
        float* ob = out + (rowbase + t) * 1024 + (w * 4 + m) * 16 + 4 * q;
        *(float4*)ob = make_float4(o[0], o[1], o[2], o[3]);
    }
}

extern "C" void kernel_launch(void* const* d_in, const int* in_sizes, int n_in,
                              void* d_out, int out_size, void* d_ws, size_t ws_size,
                              hipStream_t stream) {
    const int*   symbols   = (const int*)d_in[0];
    const float* encodings = (const float*)d_in[1];
    const float* M         = (const float*)d_in[2];
    const float* C         = (const float*)d_in[3];
    float* out   = (float*)d_out;
    float* p_out = out + (size_t)B_ * T_ * 1024;   // concat order: output, then p

    dim3 grid(B_ * (T_ / 16));                     // 1024 blocks x 512 threads
    attn_cell_kernel<<<grid, 512, 0, stream>>>(symbols, encodings, M, C, out, p_out);
}